// Round 1
// baseline (229.963 us; speedup 1.0000x reference)
//
#include <hip/hip_runtime.h>
#include <math.h>

#define W 1024
#define IMG_SZ (1024*1024)
#define N_IMG 32
#define RPC 16                      // rows per chunk
#define CPI 64                      // chunks per image: ceil(1022/16)
#define TOTAL_CHUNKS (N_IMG*CPI)    // 2048

// Load phi[y, xbase-1 .. xbase+4] into a[0..5]; halo guarded at row edges.
__device__ __forceinline__ void load_row(const float* __restrict__ img, int y,
                                         int xbase, int q, float a[6]) {
    const float* r = img + (size_t)y * W + xbase;
    const float4 v = *reinterpret_cast<const float4*>(r);
    a[0] = (q > 0)   ? r[-1] : 0.0f;
    a[1] = v.x; a[2] = v.y; a[3] = v.z; a[4] = v.w;
    a[5] = (q < 255) ? r[4]  : 0.0f;
}

// One interior pixel, exact reference op order, no FMA contraction.
__device__ __forceinline__ void pixel(const float top[6], const float mid[6],
                                      const float bot[6], int j,
                                      double& sum, double& cnt) {
#pragma clang fp contract(off)
    constexpr float TWO_H   = (float)(2.0 * 0.061);
    constexpr float FOUR_H2 = (float)(4.0 * 0.061 * 0.061);
    const float ddx = (mid[j+2] - mid[j]) / TWO_H;
    const float ddy = (bot[j+1] - top[j+1]) / TWO_H;
    const float d2  = (((bot[j+2] - bot[j]) - top[j+2]) + top[j]) / FOUR_H2;
    const float num = (d2*(ddy*ddy) - 2.0f*ddy*ddx*d2) + d2*(ddx*ddx);
    const float s   = ddx*ddx + ddy*ddy;
    const float den = s * sqrtf(s);               // s**1.5
    const float curv = num / (den + 1e-8f);
    float cr = curv*curv - 1.0f;                  // (curv/1.0f)^2 - 1 (CURV_THRESH+EPS rounds to 1.0f)
    cr = cr > 0.0f ? cr : 0.0f;                   // relu
    const float c = mid[j+1];
    const bool zc = (c*mid[j+2] < 0.0f) | (c*mid[j] < 0.0f) |
                    (c*bot[j+1] < 0.0f) | (c*top[j+1] < 0.0f);
    if (zc) { sum += (double)cr; cnt += 1.0; }
}

__global__ __launch_bounds__(256) void curv_partial(const float* __restrict__ phi,
                                                    double* __restrict__ partial,
                                                    int nb) {
    const int q = threadIdx.x;        // quad id 0..255, pixels x = 4q..4q+3
    const int xbase = q * 4;
    double sum = 0.0, cnt = 0.0;

    for (int chunk = (int)blockIdx.x; chunk < TOTAL_CHUNKS; chunk += nb) {
        const int n  = chunk >> 6;    // image
        const int ci = chunk & 63;    // chunk within image
        const int y0 = 1 + ci * RPC;
        const int yend = (y0 + RPC < 1023) ? (y0 + RPC) : 1023;  // exclusive
        const float* img = phi + (size_t)n * IMG_SZ;

        float top[6], mid[6], bot[6];
        load_row(img, y0 - 1, xbase, q, top);
        load_row(img, y0,     xbase, q, mid);

        for (int y = y0; y < yend; ++y) {
            load_row(img, y + 1, xbase, q, bot);
#pragma unroll
            for (int j = 0; j < 4; ++j) {
                const int x = xbase + j;
                if (x >= 1 && x <= 1022)
                    pixel(top, mid, bot, j, sum, cnt);
            }
#pragma unroll
            for (int k = 0; k < 6; ++k) { top[k] = mid[k]; mid[k] = bot[k]; }
        }
    }

    // wave (64-lane) shuffle reduction
    for (int off = 32; off > 0; off >>= 1) {
        sum += __shfl_down(sum, off, 64);
        cnt += __shfl_down(cnt, off, 64);
    }
    __shared__ double lsum[4], lcnt[4];
    const int lane = threadIdx.x & 63, wave = threadIdx.x >> 6;
    if (lane == 0) { lsum[wave] = sum; lcnt[wave] = cnt; }
    __syncthreads();
    if (threadIdx.x == 0) {
        partial[blockIdx.x]      = lsum[0] + lsum[1] + lsum[2] + lsum[3];
        partial[nb + blockIdx.x] = lcnt[0] + lcnt[1] + lcnt[2] + lcnt[3];
    }
}

__global__ __launch_bounds__(256) void curv_final(const double* __restrict__ partial,
                                                  int nb, float* __restrict__ out) {
    double s = 0.0, c = 0.0;
    for (int i = threadIdx.x; i < nb; i += 256) {
        s += partial[i];
        c += partial[nb + i];
    }
    for (int off = 32; off > 0; off >>= 1) {
        s += __shfl_down(s, off, 64);
        c += __shfl_down(c, off, 64);
    }
    __shared__ double lsum[4], lcnt[4];
    const int lane = threadIdx.x & 63, wave = threadIdx.x >> 6;
    if (lane == 0) { lsum[wave] = s; lcnt[wave] = c; }
    __syncthreads();
    if (threadIdx.x == 0) {
        const double S = lsum[0] + lsum[1] + lsum[2] + lsum[3];
        const double C = lcnt[0] + lcnt[1] + lcnt[2] + lcnt[3];
        out[0] = (float)(S / (C + 1e-8));
    }
}

extern "C" void kernel_launch(void* const* d_in, const int* in_sizes, int n_in,
                              void* d_out, int out_size, void* d_ws, size_t ws_size,
                              hipStream_t stream) {
    const float* phi = (const float*)d_in[0];
    float* out = (float*)d_out;
    double* partial = (double*)d_ws;

    int nb = TOTAL_CHUNKS;
    const size_t need = (size_t)nb * 2 * sizeof(double);
    if (ws_size < need) {
        nb = (int)(ws_size / (2 * sizeof(double)));
        if (nb < 1) nb = 1;
    }

    curv_partial<<<nb, 256, 0, stream>>>(phi, partial, nb);
    curv_final<<<1, 256, 0, stream>>>(partial, nb, out);
}

// Round 2
// 195.336 us; speedup vs baseline: 1.1773x; 1.1773x over previous
//
#include <hip/hip_runtime.h>
#include <math.h>

#define W 1024
#define IMG_SZ (1024*1024)
#define N_IMG 32
#define RPC 16                      // rows per chunk
#define CPI 64                      // chunks per image: ceil(1022/16)
#define TOTAL_CHUNKS (N_IMG*CPI)    // 2048

// curv = num/(den+1e-8) with ddx=Dx/(2h), ddy=Dy/(2h), d2=Dxy/(4h^2):
//   num = d2*(ddx-ddy)^2 = Dxy*(Dx-Dy)^2 / (16 h^4)
//   den = (ddx^2+ddy^2)^1.5 = (Dx^2+Dy^2)^1.5 / (8 h^3)
// => curv = Dxy*(Dx-Dy)^2 / (2h*(Dx^2+Dy^2)^1.5 + 16 h^4 * 1e-8)
#define TWO_H    0.122f
#define C_EPS    2.2153332e-12f     // 16 * 0.061^4 * 1e-8

// Load phi[y, xbase-1 .. xbase+4] into a[0..5]; halo guarded at row edges.
__device__ __forceinline__ void load_row(const float* __restrict__ img, int y,
                                         int xbase, int q, float a[6]) {
    const float* r = img + (size_t)y * W + xbase;
    const float4 v = *reinterpret_cast<const float4*>(r);
    a[0] = (q > 0)   ? r[-1] : 0.0f;
    a[1] = v.x; a[2] = v.y; a[3] = v.z; a[4] = v.w;
    a[5] = (q < 255) ? r[4]  : 0.0f;
}

__device__ __forceinline__ void pixel(const float top[6], const float mid[6],
                                      const float bot[6], int j,
                                      double& sum, int& cnt) {
    const float Dx  = mid[j+2] - mid[j];
    const float Dy  = bot[j+1] - top[j+1];
    const float Dxy = (bot[j+2] - bot[j]) - top[j+2] + top[j];
    const float dif = Dx - Dy;
    const float num = Dxy * (dif * dif);
    const float s   = Dx*Dx + Dy*Dy;
    const float den = TWO_H * (s * __builtin_amdgcn_sqrtf(s)) + C_EPS;
    const float t   = num * __builtin_amdgcn_rcpf(den);
    const float cr  = fmaxf(t*t - 1.0f, 0.0f);    // relu((curv/1)^2 - 1)
    const float c = mid[j+1];
    const bool zc = (c*mid[j+2] < 0.0f) | (c*mid[j] < 0.0f) |
                    (c*bot[j+1] < 0.0f) | (c*top[j+1] < 0.0f);
    if (zc) { sum += (double)cr; cnt += 1; }
}

__global__ __launch_bounds__(256) void curv_partial(const float* __restrict__ phi,
                                                    double* __restrict__ partial,
                                                    int nb) {
    const int q = threadIdx.x;        // quad id 0..255, pixels x = 4q..4q+3
    const int xbase = q * 4;
    double sum = 0.0;
    int cnt = 0;

    for (int chunk = (int)blockIdx.x; chunk < TOTAL_CHUNKS; chunk += nb) {
        const int n  = chunk >> 6;    // image
        const int ci = chunk & 63;    // chunk within image
        const int y0 = 1 + ci * RPC;
        const int yend = (y0 + RPC < 1023) ? (y0 + RPC) : 1023;  // exclusive
        const float* img = phi + (size_t)n * IMG_SZ;

        float top[6], mid[6], bot[6];
        load_row(img, y0 - 1, xbase, q, top);
        load_row(img, y0,     xbase, q, mid);

        for (int y = y0; y < yend; ++y) {
            load_row(img, y + 1, xbase, q, bot);
#pragma unroll
            for (int j = 0; j < 4; ++j) {
                const int x = xbase + j;
                if (x >= 1 && x <= 1022)
                    pixel(top, mid, bot, j, sum, cnt);
            }
#pragma unroll
            for (int k = 0; k < 6; ++k) { top[k] = mid[k]; mid[k] = bot[k]; }
        }
    }

    // wave (64-lane) shuffle reduction
    double dcnt = (double)cnt;
    for (int off = 32; off > 0; off >>= 1) {
        sum  += __shfl_down(sum, off, 64);
        dcnt += __shfl_down(dcnt, off, 64);
    }
    __shared__ double lsum[4], lcnt[4];
    const int lane = threadIdx.x & 63, wave = threadIdx.x >> 6;
    if (lane == 0) { lsum[wave] = sum; lcnt[wave] = dcnt; }
    __syncthreads();
    if (threadIdx.x == 0) {
        partial[blockIdx.x]      = lsum[0] + lsum[1] + lsum[2] + lsum[3];
        partial[nb + blockIdx.x] = lcnt[0] + lcnt[1] + lcnt[2] + lcnt[3];
    }
}

__global__ __launch_bounds__(256) void curv_final(const double* __restrict__ partial,
                                                  int nb, float* __restrict__ out) {
    double s = 0.0, c = 0.0;
    for (int i = threadIdx.x; i < nb; i += 256) {
        s += partial[i];
        c += partial[nb + i];
    }
    for (int off = 32; off > 0; off >>= 1) {
        s += __shfl_down(s, off, 64);
        c += __shfl_down(c, off, 64);
    }
    __shared__ double lsum[4], lcnt[4];
    const int lane = threadIdx.x & 63, wave = threadIdx.x >> 6;
    if (lane == 0) { lsum[wave] = s; lcnt[wave] = c; }
    __syncthreads();
    if (threadIdx.x == 0) {
        const double S = lsum[0] + lsum[1] + lsum[2] + lsum[3];
        const double C = lcnt[0] + lcnt[1] + lcnt[2] + lcnt[3];
        out[0] = (float)(S / (C + 1e-8));
    }
}

extern "C" void kernel_launch(void* const* d_in, const int* in_sizes, int n_in,
                              void* d_out, int out_size, void* d_ws, size_t ws_size,
                              hipStream_t stream) {
    const float* phi = (const float*)d_in[0];
    float* out = (float*)d_out;
    double* partial = (double*)d_ws;

    int nb = TOTAL_CHUNKS;
    const size_t need = (size_t)nb * 2 * sizeof(double);
    if (ws_size < need) {
        nb = (int)(ws_size / (2 * sizeof(double)));
        if (nb < 1) nb = 1;
    }

    curv_partial<<<nb, 256, 0, stream>>>(phi, partial, nb);
    curv_final<<<1, 256, 0, stream>>>(partial, nb, out);
}